// Round 3
// baseline (41.778 us; speedup 1.0000x reference)
//
#include <hip/hip_runtime.h>

// DivEncLayer via MFMA, occupancy-focused rewrite.
// Per (b,q): h = elu(x[b,q*8:+8]@W1[q] + b1[q]); LN(h); out = h@W2[q]+b2[q].
// B=16384, Q=128, S=8, U=32.
//
// One v_mfma_f32_32x32x16_bf16 per 32-row tile:
//   A lanes 0-31  (k=0..7):  whi[u][k]   = bf16(W1[q][k][u])
//   A lanes 32-63 (k=8..15): wlo[u][k-8] = bf16(W1 - whi)      (hi/lo split)
//   B lanes: every lane loads row b0+(ln&31) -> k<8 and k>=8 both get xhi
//   => D[u][b] = (whi+wlo)[u][:] . xhi[:][b]  ~ fp32-accurate W1, bf16 x
//   D layout (HW-verified): col=lane&31 -> b, row=(r&3)+8*(r>>2)+4*(lane>>5) -> u
// b1 added post-MFMA in fp32. LN+Dense2 folded:
//   out = rsqrt(var+eps)*(dot(e,g2) - mu*G) + C;  g2=gamma*W2, G=sum g2,
//   C=sum(beta*W2)+b2.
// b1/g2 live in wave-private LDS (ds_read_b128 broadcast, no VGPR cost).
// No __syncthreads at all; waves independent. 4096 blocks x 4 tiles of 32 rows.

typedef __attribute__((ext_vector_type(8))) short short8;    // 8 bf16
typedef __attribute__((ext_vector_type(16))) float f32x16;

__device__ __forceinline__ short fbits(__bf16 b) { return __builtin_bit_cast(short, b); }

__device__ __forceinline__ float elu1(float v) {
    return v > 0.f ? v : __expf(v) - 1.f;
}

__global__ __launch_bounds__(256, 8) void divenc_mfma(
    const float* __restrict__ x,      // (16384, 1024)
    const float* __restrict__ W1,     // (128, 8, 32)
    const float* __restrict__ b1,     // (128, 32)
    const float* __restrict__ gamma,  // (128, 32)
    const float* __restrict__ beta,   // (128, 32)
    const float* __restrict__ W2,     // (128, 32)
    const float* __restrict__ b2,     // (128,)
    float* __restrict__ out)          // (16384, 128)
{
    __shared__ float lp[4][32][2];    // [wave][u][{b1, g2}] — wave-private

    const int tid  = threadIdx.x;
    const int w    = tid >> 6;
    const int ln   = tid & 63;
    const int u    = ln & 31;
    const int half = ln >> 5;
    const int qt   = blockIdx.y;      // 0..31
    const int q    = qt * 4 + w;
    const int bx   = blockIdx.x;      // 0..127

    // ---- A-frag: lanes<32 = whi (k=0..7), lanes>=32 = wlo (k=8..15) ----
    short8 wfrag;
    #pragma unroll
    for (int j = 0; j < 8; ++j) {
        float f  = W1[q * 256 + j * 32 + u];
        __bf16 h = (__bf16)f;
        wfrag[j] = half ? fbits((__bf16)(f - (float)h)) : fbits(h);
    }

    // ---- params: b1,g2 -> wave-private LDS; G,C scalars ----
    float G, C;
    {
        float w2 = W2[q * 32 + u];
        float g2 = gamma[q * 32 + u] * w2;
        float bw = beta [q * 32 + u] * w2;
        if (half == 0) {
            lp[w][u][0] = b1[q * 32 + u];
            lp[w][u][1] = g2;
        }
        float gs = g2, cs = bw;
        #pragma unroll
        for (int m = 1; m < 32; m <<= 1) {
            gs += __shfl_xor(gs, m);
            cs += __shfl_xor(cs, m);
        }
        G = gs;
        C = cs + b2[q];
    }
    // wave-private LDS write->read: same-wave DS ordering, no barrier needed

    const float* xq = x + q * 8;

    // prime tile 0: both halves load the same 32 rows (addresses coalesce)
    float4 xa, xb;
    {
        const float* p = xq + (size_t)(bx * 128 + u) * 1024;
        xa = ((const float4*)p)[0];
        xb = ((const float4*)p)[1];
    }

    #pragma unroll 1
    for (int it = 0; it < 4; ++it) {
        const int b0 = bx * 128 + it * 32;

        // prefetch next tile (last iter re-reads current, L2-hot, discarded)
        const int bn = (it < 3) ? b0 + 32 : b0;
        const float* pn = xq + (size_t)(bn + u) * 1024;
        float4 na = ((const float4*)pn)[0];
        float4 nb = ((const float4*)pn)[1];

        // bf16 conversion of this lane's row (hi only; W1 carries the lo fix)
        float xf[8] = {xa.x, xa.y, xa.z, xa.w, xb.x, xb.y, xb.z, xb.w};
        short8 xfrag;
        #pragma unroll
        for (int j = 0; j < 8; ++j) xfrag[j] = fbits((__bf16)xf[j]);

        f32x16 zacc = {};
        f32x16 acc = __builtin_amdgcn_mfma_f32_32x32x16_bf16(wfrag, xfrag, zacc, 0, 0, 0);

        // ---- finish: e = elu(acc + b1); sum/ss/dot reductions over u ----
        float2 sum2 = {0.f, 0.f}, ss2 = {0.f, 0.f}, dot2 = {0.f, 0.f};
        #pragma unroll
        for (int r = 0; r < 16; r += 2) {
            int u0 = (r & 3) + 8 * (r >> 2) + 4 * half;
            float4 bg = *(const float4*)&lp[w][u0][0];   // {b1[u0],g2[u0],b1[u0+1],g2[u0+1]}
            float e0 = elu1(acc[r]     + bg.x);
            float e1 = elu1(acc[r + 1] + bg.z);
            sum2.x += e0;
            sum2.y += e1;
            ss2.x = fmaf(e0, e0, ss2.x);
            ss2.y = fmaf(e1, e1, ss2.y);
            dot2.x = fmaf(e0, bg.y, dot2.x);
            dot2.y = fmaf(e1, bg.w, dot2.y);
        }
        float sum = sum2.x + sum2.y;
        float ss  = ss2.x + ss2.y;
        float dot = dot2.x + dot2.y;
        sum += __shfl_xor(sum, 32);
        ss  += __shfl_xor(ss, 32);
        dot += __shfl_xor(dot, 32);
        float mu  = sum * 0.03125f;
        float var = fmaf(-mu, mu, ss * 0.03125f);
        float inv = rsqrtf(var + 1e-3f);
        float res = fmaf(inv, fmaf(-mu, G, dot), C);

        if (half == 0)
            out[(size_t)(b0 + u) * 128 + q] = res;

        xa = na;
        xb = nb;
    }
}

extern "C" void kernel_launch(void* const* d_in, const int* in_sizes, int n_in,
                              void* d_out, int out_size, void* d_ws, size_t ws_size,
                              hipStream_t stream) {
    const float* x     = (const float*)d_in[0];
    const float* W1    = (const float*)d_in[1];
    const float* b1    = (const float*)d_in[2];
    const float* gamma = (const float*)d_in[3];
    const float* beta  = (const float*)d_in[4];
    const float* W2    = (const float*)d_in[5];
    const float* b2    = (const float*)d_in[6];
    float* out = (float*)d_out;

    dim3 grid(128, 32);   // (b-tile groups of 128 rows, q-tiles of 4)
    divenc_mfma<<<grid, 256, 0, stream>>>(x, W1, b1, gamma, beta, W2, b2, out);
}

// Round 4
// 34.778 us; speedup vs baseline: 1.2013x; 1.2013x over previous
//
#include <hip/hip_runtime.h>

// DivEncLayer via MFMA. Per (b,q): h = elu(x[b,q*8:+8]@W1[q] + b1[q]); LN; out=h@W2[q]+b2[q].
// B=16384, Q=128, S=8, U=32.
//
// One v_mfma_f32_32x32x16_bf16 per 32-row tile, C-in = b1 (fp32 exact):
//   A lanes 0-31  (k=0..7):  whi[u][k]   = bf16(W1[q][k][u])
//   A lanes 32-63 (k=8..15): wlo[u][k-8] = bf16(W1 - whi)     (hi/lo split)
//   B: every lane loads row b0+(ln&31); same xfrag in both k-halves
//   => D[u][b] = (whi+wlo)[u][:].xhi[:][b] + b1[u]
//   D layout: col=lane&31 -> b, row r -> u=(r&3)+8*(r>>2)+4*(lane>>5)  [HW-verified]
// LN+Dense2 folded: out = rsqrt(var+eps)*(dot(e,g2) - mu*G) + C
//   g2=gamma*W2, G=sum g2, C=sum(beta*W2)+b2.
// Params per lane are 4 contiguous float4 chunks (u = 4*half+8c..+3) -> vector loads.
// Output staged in padded LDS (stride 5), one float4 store per row (write-exact).
// Grid (128,32) = 4096 blocks x 4 tiles of 32 rows; x prefetched 1 tile ahead.

typedef __attribute__((ext_vector_type(8))) short short8;    // 8 bf16
typedef __attribute__((ext_vector_type(16))) float f32x16;

__device__ __forceinline__ short fbits(__bf16 b) { return __builtin_bit_cast(short, b); }

__device__ __forceinline__ float elu1(float v) {
    return v > 0.f ? v : __expf(v) - 1.f;
}

__global__ __launch_bounds__(256, 4) void divenc_mfma(
    const float* __restrict__ x,      // (16384, 1024)
    const float* __restrict__ W1,     // (128, 8, 32)
    const float* __restrict__ b1,     // (128, 32)
    const float* __restrict__ gamma,  // (128, 32)
    const float* __restrict__ beta,   // (128, 32)
    const float* __restrict__ W2,     // (128, 32)
    const float* __restrict__ b2,     // (128,)
    float* __restrict__ out)          // (16384, 128)
{
    __shared__ float lout[2][32 * 5];  // [buf][row*5 + w], padded stride 5

    const int tid  = threadIdx.x;
    const int w    = tid >> 6;
    const int ln   = tid & 63;
    const int u    = ln & 31;
    const int half = ln >> 5;
    const int qt   = blockIdx.y;      // 0..31
    const int q    = qt * 4 + w;
    const int bx   = blockIdx.x;      // 0..127

    // ---- A-frag: lanes<32 = whi (k=0..7), lanes>=32 = wlo (k=8..15) ----
    short8 wfrag;
    #pragma unroll
    for (int j = 0; j < 8; ++j) {
        float f  = W1[q * 256 + j * 32 + u];
        __bf16 h = (__bf16)f;
        wfrag[j] = half ? fbits((__bf16)(f - (float)h)) : fbits(h);
    }

    // ---- params: biasr (MFMA C-in), g2r regs; G,C scalars. Vector loads: ----
    // r=4c+j -> u0 = 4*half + 8*c + j  (4 contiguous float4 chunks per lane)
    f32x16 biasr;
    f32x16 g2r;
    float G, C;
    {
        float gs = 0.f, cs = 0.f;
        #pragma unroll
        for (int c = 0; c < 4; ++c) {
            const int ub = q * 32 + 4 * half + 8 * c;
            float4 b1v = *(const float4*)&b1[ub];
            float4 gav = *(const float4*)&gamma[ub];
            float4 w2v = *(const float4*)&W2[ub];
            float4 bev = *(const float4*)&beta[ub];
            #pragma unroll
            for (int j = 0; j < 4; ++j) {
                float g2 = ((const float*)&gav)[j] * ((const float*)&w2v)[j];
                biasr[4 * c + j] = ((const float*)&b1v)[j];
                g2r[4 * c + j]   = g2;
                gs += g2;
                cs += ((const float*)&bev)[j] * ((const float*)&w2v)[j];
            }
        }
        gs += __shfl_xor(gs, 32);   // other half holds the other 16 u's
        cs += __shfl_xor(cs, 32);
        G = gs;
        C = cs + b2[q];
    }

    const float* xq = x + q * 8;

    // prime tile 0: all lanes load row b0+(ln&31) (dup addresses coalesce)
    float4 xa, xb;
    {
        const float* p = xq + (size_t)(bx * 128 + u) * 1024;
        xa = ((const float4*)p)[0];
        xb = ((const float4*)p)[1];
    }

    #pragma unroll 1
    for (int it = 0; it < 4; ++it) {
        const int b0 = bx * 128 + it * 32;

        // prefetch next tile (last iter re-reads current, L2-hot, discarded)
        const int bn = (it < 3) ? b0 + 32 : b0;
        const float* pn = xq + (size_t)(bn + u) * 1024;
        float4 na = ((const float4*)pn)[0];
        float4 nb = ((const float4*)pn)[1];

        // bf16 convert this lane's row (hi only; W1 carries the lo fix)
        float xf[8] = {xa.x, xa.y, xa.z, xa.w, xb.x, xb.y, xb.z, xb.w};
        short8 xfrag;
        #pragma unroll
        for (int j = 0; j < 8; ++j) xfrag[j] = fbits((__bf16)xf[j]);

        f32x16 acc = __builtin_amdgcn_mfma_f32_32x32x16_bf16(wfrag, xfrag, biasr, 0, 0, 0);

        // ---- finish: e = elu(acc); sum/ss/dot over u ----
        float sum = 0.f, ss = 0.f, dot = 0.f;
        #pragma unroll
        for (int r = 0; r < 16; ++r) {
            float e = elu1(acc[r]);
            sum += e;
            ss  = fmaf(e, e, ss);
            dot = fmaf(e, g2r[r], dot);
        }
        sum += __shfl_xor(sum, 32);
        ss  += __shfl_xor(ss, 32);
        dot += __shfl_xor(dot, 32);
        float mu  = sum * 0.03125f;
        float var = fmaf(-mu, mu, ss * 0.03125f);
        float inv = rsqrtf(var + 1e-3f);
        float res = fmaf(inv, fmaf(-mu, G, dot), C);

        // ---- gather 4 q's per row in LDS, one float4 store per row ----
        if (half == 0)
            lout[it & 1][u * 5 + w] = res;
        __syncthreads();

        if (tid < 32) {
            const float* lb = lout[it & 1];
            float4 o;
            o.x = lb[tid * 5 + 0];
            o.y = lb[tid * 5 + 1];
            o.z = lb[tid * 5 + 2];
            o.w = lb[tid * 5 + 3];
            *(float4*)(out + (size_t)(b0 + tid) * 128 + qt * 4) = o;
        }

        xa = na;
        xb = nb;
    }
}

extern "C" void kernel_launch(void* const* d_in, const int* in_sizes, int n_in,
                              void* d_out, int out_size, void* d_ws, size_t ws_size,
                              hipStream_t stream) {
    const float* x     = (const float*)d_in[0];
    const float* W1    = (const float*)d_in[1];
    const float* b1    = (const float*)d_in[2];
    const float* gamma = (const float*)d_in[3];
    const float* beta  = (const float*)d_in[4];
    const float* W2    = (const float*)d_in[5];
    const float* b2    = (const float*)d_in[6];
    float* out = (float*)d_out;

    dim3 grid(128, 32);   // (b-groups of 128 rows, q-tiles of 4)
    divenc_mfma<<<grid, 256, 0, stream>>>(x, W1, b1, gamma, beta, W2, b2, out);
}